// Round 1
// 667.506 us; speedup vs baseline: 1.0252x; 1.0252x over previous
//
#include <hip/hip_runtime.h>
#include <hip/hip_bf16.h>

typedef __attribute__((ext_vector_type(8))) short short8;
typedef __attribute__((ext_vector_type(4))) float float4v;

#define BM 128
#define BK 32
#define LDSK 40   // old fallback path: padded bf16 row length

struct alignas(8) BF4 { unsigned short x, y, z, w; };
struct alignas(16) BF8 { unsigned short s[8]; };
struct alignas(16) I4 { int x, y, z, w; };

__device__ __forceinline__ unsigned short f2bf(float f) {
    union { float f; unsigned u; } v; v.f = f;
    unsigned u = v.u + (0x7FFFu + ((v.u >> 16) & 1u));   // round-to-nearest-even
    return (unsigned short)(u >> 16);
}

__device__ __forceinline__ int find_expert(const int* __restrict__ bspe, int row0) {
    int e = 0, off = 0;
    #pragma unroll
    for (int i = 0; i < 8; ++i) {
        int s = bspe[i];
        if (row0 < off + s) { e = i; break; }
        off += s;
    }
    return e;
}

// 16B-per-lane async global->LDS. LDS dest must be wave-uniform base; HW adds lane*16.
__device__ __forceinline__ void gload_lds16(const unsigned short* g, unsigned short* l) {
    __builtin_amdgcn_global_load_lds(
        (const __attribute__((address_space(1))) void*)g,
        (__attribute__((address_space(3))) void*)l, 16, 0, 0);
}

// ---------------------------------------------------------------------------
// Pre-pass: fp32 -> bf16 (RNE), vectorized 8 elem/thread. Pure BW-bound.
// ---------------------------------------------------------------------------
__global__ __launch_bounds__(256) void f32_to_bf16(const float* __restrict__ src,
                                                   unsigned short* __restrict__ dst,
                                                   long n) {
    const long stride = (long)gridDim.x * 256 * 8;
    for (long i = ((long)blockIdx.x * 256 + threadIdx.x) * 8; i < n; i += stride) {
        const float4 v0 = *(const float4*)(src + i);
        const float4 v1 = *(const float4*)(src + i + 4);
        BF8 o;
        o.s[0] = f2bf(v0.x); o.s[1] = f2bf(v0.y); o.s[2] = f2bf(v0.z); o.s[3] = f2bf(v0.w);
        o.s[4] = f2bf(v1.x); o.s[5] = f2bf(v1.y); o.s[6] = f2bf(v1.z); o.s[7] = f2bf(v1.w);
        *(BF8*)(dst + i) = o;
    }
}

// ---------------------------------------------------------------------------
// NEW PATH: bf16 GEMMs with global_load_lds staging (m97 structure).
// LDS tiles are LINEAR [128][32] bf16 (8 KB each) -- required by global_load_lds.
// Per K-step: 8 issues of 16B/lane fill both tiles; 8 ds_read_b128; 16 MFMA/wave.
// ---------------------------------------------------------------------------
__global__ __launch_bounds__(256) void moe_up_gate_bf(
    const unsigned short* __restrict__ xb, const unsigned short* __restrict__ wb,
    const int* __restrict__ bspe, unsigned short* __restrict__ hws) {
    __shared__ alignas(16) unsigned short As[128 * 32];
    __shared__ alignas(16) unsigned short Bs[128 * 32];

    const int t = threadIdx.x;
    const int lane = t & 63;
    const int w = t >> 6;
    const int wr = w >> 1, wc = w & 1;
    const int bm = blockIdx.y;
    const int h0 = blockIdx.x * 64;
    const int row0 = bm * BM;

    const int e = find_expert(bspe, row0);

    const unsigned short* abase = xb + (long)row0 * 2048;
    const unsigned short* bup = wb + ((long)e * 2048 + h0) * 2048;           // up rows
    const unsigned short* bgt = wb + ((long)e * 2048 + 1024 + h0) * 2048;    // gate rows

    float4v acc[4][4];
    #pragma unroll
    for (int m = 0; m < 4; ++m)
        #pragma unroll
        for (int n = 0; n < 4; ++n)
            acc[m][n] = (float4v){0.f, 0.f, 0.f, 0.f};

    // staging geometry: issue j covers tile rows [j*16, j*16+16); lane -> (row j*16+(lane>>2), col (lane&3)*8)
    const int j0 = w, j1 = w + 4;
    const int srow = lane >> 2;
    const int scol = (lane & 3) << 3;
    const unsigned short* a0 = abase + (long)(j0 * 16 + srow) * 2048 + scol;
    const unsigned short* a1 = abase + (long)(j1 * 16 + srow) * 2048 + scol;
    const unsigned short* b0 = bup + (long)(j0 * 16 + srow) * 2048 + scol;          // rows 0..63: up
    const unsigned short* b1 = bgt + (long)((j1 - 4) * 16 + srow) * 2048 + scol;    // rows 64..127: gate

    const int k8 = (lane >> 4) << 3;
    const int am = wr * 64 + (lane & 15);
    const int l15 = lane & 15;

    for (int k0 = 0; k0 < 2048; k0 += BK) {
        __syncthreads();                      // prior iter's ds_reads done
        gload_lds16(a0 + k0, As + j0 * 512);
        gload_lds16(a1 + k0, As + j1 * 512);
        gload_lds16(b0 + k0, Bs + j0 * 512);
        gload_lds16(b1 + k0, Bs + j1 * 512);
        __syncthreads();                      // compiler drains vmcnt(0) before barrier

        short8 a[4], b[4];
        #pragma unroll
        for (int m = 0; m < 4; ++m)
            a[m] = *(const short8*)(As + (am + m * 16) * 32 + k8);
        #pragma unroll
        for (int n = 0; n < 4; ++n) {
            const int rb = (n < 2) ? (wc * 32 + n * 16) : (64 + wc * 32 + (n - 2) * 16);
            b[n] = *(const short8*)(Bs + (rb + l15) * 32 + k8);
        }
        #pragma unroll
        for (int m = 0; m < 4; ++m)
            #pragma unroll
            for (int n = 0; n < 4; ++n)
                acc[m][n] = __builtin_amdgcn_mfma_f32_16x16x32_bf16(a[m], b[n], acc[m][n], 0, 0, 0);
    }

    // Epilogue: h = silu(up) * gate. acc[m][n] (up) pairs with acc[m][n+2] (gate).
    const int rbase = row0 + wr * 64 + (lane >> 4) * 4;
    const int cbase = h0 + wc * 32 + l15;
    #pragma unroll
    for (int m = 0; m < 4; ++m)
        #pragma unroll
        for (int n = 0; n < 2; ++n)
            #pragma unroll
            for (int q = 0; q < 4; ++q) {
                const float u = acc[m][n][q];
                const float g = acc[m][n + 2][q];
                const float s = u / (1.f + __expf(-u));
                const int row = rbase + m * 16 + q;
                const int col = cbase + n * 16;
                hws[(long)row * 1024 + col] = f2bf(s * g);
            }
}

__global__ __launch_bounds__(256) void moe_down_bf(
    const unsigned short* __restrict__ hws, const unsigned short* __restrict__ wdb,
    const int* __restrict__ bspe, float* __restrict__ out) {
    __shared__ alignas(16) unsigned short As[128 * 32];
    __shared__ alignas(16) unsigned short Bs[128 * 32];

    const int t = threadIdx.x;
    const int lane = t & 63;
    const int w = t >> 6;
    const int wr = w >> 1, wc = w & 1;
    const int bm = blockIdx.y;
    const int n0 = blockIdx.x * BM;
    const int row0 = bm * BM;

    const int e = find_expert(bspe, row0);

    const unsigned short* abase = hws + (long)row0 * 1024;
    const unsigned short* bbase = wdb + (long)n0 * 8192 + e * 1024;

    float4v acc[4][4];
    #pragma unroll
    for (int m = 0; m < 4; ++m)
        #pragma unroll
        for (int n = 0; n < 4; ++n)
            acc[m][n] = (float4v){0.f, 0.f, 0.f, 0.f};

    const int j0 = w, j1 = w + 4;
    const int srow = lane >> 2;
    const int scol = (lane & 3) << 3;
    const unsigned short* a0 = abase + (long)(j0 * 16 + srow) * 1024 + scol;
    const unsigned short* a1 = abase + (long)(j1 * 16 + srow) * 1024 + scol;
    const unsigned short* b0 = bbase + (long)(j0 * 16 + srow) * 8192 + scol;
    const unsigned short* b1 = bbase + (long)(j1 * 16 + srow) * 8192 + scol;

    const int k8 = (lane >> 4) << 3;
    const int am = wr * 64 + (lane & 15);
    const int l15 = lane & 15;

    for (int k0 = 0; k0 < 1024; k0 += BK) {
        __syncthreads();
        gload_lds16(a0 + k0, As + j0 * 512);
        gload_lds16(a1 + k0, As + j1 * 512);
        gload_lds16(b0 + k0, Bs + j0 * 512);
        gload_lds16(b1 + k0, Bs + j1 * 512);
        __syncthreads();

        short8 a[4], b[4];
        #pragma unroll
        for (int m = 0; m < 4; ++m)
            a[m] = *(const short8*)(As + (am + m * 16) * 32 + k8);
        #pragma unroll
        for (int n = 0; n < 4; ++n)
            b[n] = *(const short8*)(Bs + (wc * 64 + n * 16 + l15) * 32 + k8);
        #pragma unroll
        for (int m = 0; m < 4; ++m)
            #pragma unroll
            for (int n = 0; n < 4; ++n)
                acc[m][n] = __builtin_amdgcn_mfma_f32_16x16x32_bf16(a[m], b[n], acc[m][n], 0, 0, 0);
    }

    const int rbase = row0 + wr * 64 + (lane >> 4) * 4;
    const int cbase = n0 + wc * 64 + l15;
    #pragma unroll
    for (int m = 0; m < 4; ++m)
        #pragma unroll
        for (int n = 0; n < 4; ++n)
            #pragma unroll
            for (int q = 0; q < 4; ++q)
                out[(long)(rbase + m * 16 + q) * 2048 + cbase + n * 16] = acc[m][n][q];
}

// ---------------------------------------------------------------------------
// OLD PATH (fallback if workspace too small): fused fp32->bf16 staging kernels.
// Verbatim from the previous verified kernel.
// ---------------------------------------------------------------------------
__device__ __forceinline__ void stage_f32_tile(const float* __restrict__ src, long ld,
                                               unsigned short* lds, int t) {
    const int rr  = t >> 3;
    const int col = (t & 7) << 2;
    #pragma unroll
    for (int r = 0; r < 4; ++r) {
        const int row = rr + r * 32;
        const float4 v = *(const float4*)(src + (long)row * ld + col);
        BF4 o; o.x = f2bf(v.x); o.y = f2bf(v.y); o.z = f2bf(v.z); o.w = f2bf(v.w);
        *(BF4*)(lds + row * LDSK + col) = o;
    }
}

__global__ __launch_bounds__(256) void moe_up_gate(
    const float* __restrict__ x, const float* __restrict__ wug,
    const int* __restrict__ bspe, unsigned short* __restrict__ hws) {
    __shared__ alignas(16) unsigned short As[BM * LDSK];
    __shared__ alignas(16) unsigned short Bs[BM * LDSK];

    const int t = threadIdx.x;
    const int lane = t & 63;
    const int w = t >> 6;
    const int wr = w >> 1, wc = w & 1;
    const int bm = blockIdx.y;
    const int h0 = blockIdx.x * 64;
    const int row0 = bm * BM;

    const int e = find_expert(bspe, row0);

    const float* abase = x + (long)row0 * 2048;
    const float* bup = wug + ((long)e * 2048 + h0) * 2048;
    const float* bgt = wug + ((long)e * 2048 + 1024 + h0) * 2048;

    float4v acc[4][4];
    #pragma unroll
    for (int m = 0; m < 4; ++m)
        #pragma unroll
        for (int n = 0; n < 4; ++n)
            acc[m][n] = (float4v){0.f, 0.f, 0.f, 0.f};

    const int k8 = (lane >> 4) << 3;
    const int am = wr * 64 + (lane & 15);
    const int l15 = lane & 15;

    for (int k0 = 0; k0 < 2048; k0 += BK) {
        __syncthreads();
        stage_f32_tile(abase + k0, 2048, As, t);
        {
            const int rr  = t >> 3;
            const int col = (t & 7) << 2;
            #pragma unroll
            for (int r = 0; r < 4; ++r) {
                const int row = rr + r * 32;
                const float* p = (row < 64 ? bup + (long)row * 2048
                                           : bgt + (long)(row - 64) * 2048) + k0 + col;
                const float4 v = *(const float4*)p;
                BF4 o; o.x = f2bf(v.x); o.y = f2bf(v.y); o.z = f2bf(v.z); o.w = f2bf(v.w);
                *(BF4*)(Bs + row * LDSK + col) = o;
            }
        }
        __syncthreads();

        short8 a[4], b[4];
        #pragma unroll
        for (int m = 0; m < 4; ++m)
            a[m] = *(const short8*)(As + (am + m * 16) * LDSK + k8);
        #pragma unroll
        for (int n = 0; n < 4; ++n) {
            const int rb = (n < 2) ? (wc * 32 + n * 16) : (64 + wc * 32 + (n - 2) * 16);
            b[n] = *(const short8*)(Bs + (rb + l15) * LDSK + k8);
        }
        #pragma unroll
        for (int m = 0; m < 4; ++m)
            #pragma unroll
            for (int n = 0; n < 4; ++n)
                acc[m][n] = __builtin_amdgcn_mfma_f32_16x16x32_bf16(a[m], b[n], acc[m][n], 0, 0, 0);
    }

    const int rbase = row0 + wr * 64 + (lane >> 4) * 4;
    const int cbase = h0 + wc * 32 + l15;
    #pragma unroll
    for (int m = 0; m < 4; ++m)
        #pragma unroll
        for (int n = 0; n < 2; ++n)
            #pragma unroll
            for (int q = 0; q < 4; ++q) {
                const float u = acc[m][n][q];
                const float g = acc[m][n + 2][q];
                const float s = u / (1.f + __expf(-u));
                const int row = rbase + m * 16 + q;
                const int col = cbase + n * 16;
                hws[(long)row * 1024 + col] = f2bf(s * g);
            }
}

__global__ __launch_bounds__(256) void moe_down(
    const unsigned short* __restrict__ hws, const float* __restrict__ wd,
    const int* __restrict__ bspe, float* __restrict__ out) {
    __shared__ alignas(16) unsigned short As[BM * LDSK];
    __shared__ alignas(16) unsigned short Bs[BM * LDSK];

    const int t = threadIdx.x;
    const int lane = t & 63;
    const int w = t >> 6;
    const int wr = w >> 1, wc = w & 1;
    const int bm = blockIdx.y;
    const int n0 = blockIdx.x * BM;
    const int row0 = bm * BM;

    const int e = find_expert(bspe, row0);

    const unsigned short* abase = hws + (long)row0 * 1024;
    const float* bbase = wd + (long)n0 * 8192 + e * 1024;

    float4v acc[4][4];
    #pragma unroll
    for (int m = 0; m < 4; ++m)
        #pragma unroll
        for (int n = 0; n < 4; ++n)
            acc[m][n] = (float4v){0.f, 0.f, 0.f, 0.f};

    const int k8 = (lane >> 4) << 3;
    const int am = wr * 64 + (lane & 15);
    const int l15 = lane & 15;

    for (int k0 = 0; k0 < 1024; k0 += BK) {
        __syncthreads();
        {
            const int row = t >> 2;
            const int col = (t & 3) << 3;
            #pragma unroll
            for (int r = 0; r < 2; ++r) {
                const I4 v = *(const I4*)(abase + (long)(row + r * 64) * 1024 + k0 + col);
                *(I4*)(As + (row + r * 64) * LDSK + col) = v;
            }
        }
        stage_f32_tile(bbase + k0, 8192, Bs, t);
        __syncthreads();

        short8 a[4], b[4];
        #pragma unroll
        for (int m = 0; m < 4; ++m)
            a[m] = *(const short8*)(As + (am + m * 16) * LDSK + k8);
        #pragma unroll
        for (int n = 0; n < 4; ++n)
            b[n] = *(const short8*)(Bs + (wc * 64 + n * 16 + l15) * LDSK + k8);
        #pragma unroll
        for (int m = 0; m < 4; ++m)
            #pragma unroll
            for (int n = 0; n < 4; ++n)
                acc[m][n] = __builtin_amdgcn_mfma_f32_16x16x32_bf16(a[m], b[n], acc[m][n], 0, 0, 0);
    }

    const int rbase = row0 + wr * 64 + (lane >> 4) * 4;
    const int cbase = n0 + wc * 64 + l15;
    #pragma unroll
    for (int m = 0; m < 4; ++m)
        #pragma unroll
        for (int n = 0; n < 4; ++n)
            #pragma unroll
            for (int q = 0; q < 4; ++q)
                out[(long)(rbase + m * 16 + q) * 2048 + cbase + n * 16] = acc[m][n][q];
}

// ---------------------------------------------------------------------------
extern "C" void kernel_launch(void* const* d_in, const int* in_sizes, int n_in,
                              void* d_out, int out_size, void* d_ws, size_t ws_size,
                              hipStream_t stream) {
    const float* x   = (const float*)d_in[0];
    const float* wug = (const float*)d_in[1];
    const float* wd  = (const float*)d_in[2];
    const int*  bspe = (const int*)d_in[3];
    float* out = (float*)d_out;

    const size_t SZ_XB  = 16384UL * 2048UL * 2UL;   // 67.1 MB bf16 x
    const size_t SZ_WB  = 16384UL * 2048UL * 2UL;   // 67.1 MB bf16 w_up_gate
    const size_t SZ_H   = 16384UL * 1024UL * 2UL;   // 33.6 MB bf16 h
    const size_t NEED   = SZ_XB + SZ_WB + SZ_H;     // 160 MiB (wd_bf overlays dead x region)

    if (ws_size >= NEED) {
        unsigned short* xb  = (unsigned short*)d_ws;
        unsigned short* wb  = (unsigned short*)((char*)d_ws + SZ_XB);
        unsigned short* hws = (unsigned short*)((char*)d_ws + SZ_XB + SZ_WB);
        unsigned short* wdb = (unsigned short*)d_ws;   // overlay: x_bf dead after up_gate

        f32_to_bf16<<<2048, 256, 0, stream>>>(x,   xb,  16384L * 2048L);
        f32_to_bf16<<<2048, 256, 0, stream>>>(wug, wb,  16384L * 2048L);
        moe_up_gate_bf<<<dim3(16, 128), dim3(256), 0, stream>>>(xb, wb, bspe, hws);
        f32_to_bf16<<<1024, 256, 0, stream>>>(wd,  wdb, 2048L * 8192L);
        moe_down_bf<<<dim3(16, 128), dim3(256), 0, stream>>>(hws, wdb, bspe, out);
    } else {
        unsigned short* hws = (unsigned short*)d_ws;   // 33.5 MB
        moe_up_gate<<<dim3(16, 128), dim3(256), 0, stream>>>(x, wug, bspe, hws);
        moe_down  <<<dim3(16, 128), dim3(256), 0, stream>>>(hws, wd, bspe, out);
    }
}

// Round 2
// 589.634 us; speedup vs baseline: 1.1606x; 1.1321x over previous
//
#include <hip/hip_runtime.h>
#include <hip/hip_bf16.h>

typedef __attribute__((ext_vector_type(8))) short short8;
typedef __attribute__((ext_vector_type(4))) float float4v;

#define BM 128
#define BK 32
#define LDSK 40   // old fallback path

struct alignas(8) BF4 { unsigned short x, y, z, w; };
struct alignas(16) BF8 { unsigned short s[8]; };
struct alignas(16) I4 { int x, y, z, w; };

__device__ __forceinline__ unsigned short f2bf(float f) {
    union { float f; unsigned u; } v; v.f = f;
    unsigned u = v.u + (0x7FFFu + ((v.u >> 16) & 1u));   // RNE
    return (unsigned short)(u >> 16);
}

__device__ __forceinline__ int find_expert(const int* __restrict__ bspe, int row0) {
    int e = 0, off = 0;
    #pragma unroll
    for (int i = 0; i < 8; ++i) {
        int s = bspe[i];
        if (row0 < off + s) { e = i; break; }
        off += s;
    }
    return e;
}

__device__ __forceinline__ void gload_lds16(const unsigned short* g, unsigned short* l) {
    __builtin_amdgcn_global_load_lds(
        (const __attribute__((address_space(1))) void*)g,
        (__attribute__((address_space(3))) void*)l, 16, 0, 0);
}

// ---------------------------------------------------------------------------
// fp32 -> bf16 pre-pass (BW-bound)
// ---------------------------------------------------------------------------
__global__ __launch_bounds__(256) void f32_to_bf16(const float* __restrict__ src,
                                                   unsigned short* __restrict__ dst,
                                                   long n) {
    const long stride = (long)gridDim.x * 256 * 8;
    for (long i = ((long)blockIdx.x * 256 + threadIdx.x) * 8; i < n; i += stride) {
        const float4 v0 = *(const float4*)(src + i);
        const float4 v1 = *(const float4*)(src + i + 4);
        BF8 o;
        o.s[0] = f2bf(v0.x); o.s[1] = f2bf(v0.y); o.s[2] = f2bf(v0.z); o.s[3] = f2bf(v0.w);
        o.s[4] = f2bf(v1.x); o.s[5] = f2bf(v1.y); o.s[6] = f2bf(v1.z); o.s[7] = f2bf(v1.w);
        *(BF8*)(dst + i) = o;
    }
}

// ===========================================================================
// 8-wave 256x256 deep-pipelined GEMM kernels (T3+T4 counted vmcnt, T2 swizzle,
// T5 setprio).  LDS layout per operand: [buf:2][ks:2][256 rows][32 cols] bf16,
// 16 KiB per (buf,ks) region, 64 KiB per operand, 128 KiB total.
// Swizzle: 16B granule g' = g ^ ((row>>1)&3) inside each 64 B row.
//   stage (linear LDS dest, pre-swizzled global src): lane l of a block-wide
//     issue covers row = i*128 + w*16 + (l>>2), src col granule (l&3)^((l>>3)&3)
//   read: granule (lane>>4) ^ (((lane&15)>>1)&3)  -- same involution.
// Schedule per K-tile t (buf = t&1), 4 phases:
//   ph0: rd B(ks0)+A(ks0,mh0) | stage A(t+1,ks1)            | bar lgkm0 MMA bar
//   ph1: rd A(ks0,mh1)        | stage B(t+1,ks1)  vmcnt(8)  | bar lgkm0 MMA bar
//   ph2: rd B(ks1)+A(ks1,mh0) | stage A(t+2,ks0)            | bar lgkm0 MMA bar
//   ph3: rd A(ks1,mh1)        | stage B(t+2,ks0)  vmcnt(8)  | bar lgkm0 MMA bar
// vmcnt derivation (2 loads/thread/phase): half consumed at ph0 was the last
// issue 8 loads ago -> vmcnt(8); tail: ph1 t==nkt-1 -> 0; ph3 t==nkt-2 -> 4.
// The vmcnt asm("memory") fences also order stage-writes vs prior LDS reads.
// ===========================================================================
#define BAR() __builtin_amdgcn_s_barrier()
#define WAITV(n) asm volatile("s_waitcnt vmcnt(" #n ")" ::: "memory")
#define WAITL0() do { asm volatile("s_waitcnt lgkmcnt(0)" ::: "memory"); \
                      __builtin_amdgcn_sched_barrier(0); } while (0)

#define STG_A(tt, kss) do { \
    gload_lds16(pA0 + (long)(tt) * 64 + (kss) * 32, As + ((((tt)&1)*2 + (kss))*8192) + 0*4096 + w*512); \
    gload_lds16(pA1 + (long)(tt) * 64 + (kss) * 32, As + ((((tt)&1)*2 + (kss))*8192) + 1*4096 + w*512); \
} while (0)
#define STG_B(tt, kss) do { \
    gload_lds16(pB0 + (long)(tt) * 64 + (kss) * 32, Bs + ((((tt)&1)*2 + (kss))*8192) + 0*4096 + w*512); \
    gload_lds16(pB1 + (long)(tt) * 64 + (kss) * 32, Bs + ((((tt)&1)*2 + (kss))*8192) + 1*4096 + w*512); \
} while (0)

#define RD_A(buf_, ks_, mh_) do { \
    const unsigned short* _p = As + (((buf_)*2 + (ks_))*8192) + gA + (arow + (mh_)*64)*32; \
    a[0] = *(const short8*)(_p);        a[1] = *(const short8*)(_p + 512); \
    a[2] = *(const short8*)(_p + 1024); a[3] = *(const short8*)(_p + 1536); \
} while (0)
#define RD_B(buf_, ks_) do { \
    const unsigned short* _p = Bs + (((buf_)*2 + (ks_))*8192) + gA + brow*32; \
    b[0] = *(const short8*)(_p);        b[1] = *(const short8*)(_p + 512); \
    b[2] = *(const short8*)(_p + 1024); b[3] = *(const short8*)(_p + 1536); \
} while (0)

#define MMA(mh_) do { \
    __builtin_amdgcn_s_setprio(1); \
    _Pragma("unroll") \
    for (int _j = 0; _j < 4; ++_j) \
        _Pragma("unroll") \
        for (int _n = 0; _n < 4; ++_n) \
            acc[(mh_)*4 + _j][_n] = __builtin_amdgcn_mfma_f32_16x16x32_bf16(a[_j], b[_n], acc[(mh_)*4 + _j][_n], 0, 0, 0); \
    __builtin_amdgcn_s_setprio(0); \
} while (0)

#define KLOOP(NKT) \
    STG_A(0, 0); STG_B(0, 0); \
    STG_A(0, 1); STG_B(0, 1); \
    STG_A(1, 0); STG_B(1, 0); \
    WAITV(8); \
    BAR(); \
    for (int t = 0; t < (NKT); ++t) { \
        const int buf = t & 1; \
        short8 a[4], b[4]; \
        /* ph0 */ \
        RD_B(buf, 0); RD_A(buf, 0, 0); \
        if (t < (NKT) - 1) STG_A(t + 1, 1); \
        BAR(); WAITL0(); \
        MMA(0); \
        BAR(); \
        /* ph1 */ \
        RD_A(buf, 0, 1); \
        if (t < (NKT) - 1) { STG_B(t + 1, 1); WAITV(8); } else { WAITV(0); } \
        BAR(); WAITL0(); \
        MMA(1); \
        BAR(); \
        /* ph2 */ \
        RD_B(buf, 1); RD_A(buf, 1, 0); \
        if (t < (NKT) - 2) STG_A(t + 2, 0); \
        BAR(); WAITL0(); \
        MMA(0); \
        BAR(); \
        /* ph3 */ \
        RD_A(buf, 1, 1); \
        if (t < (NKT) - 2) { STG_B(t + 2, 0); WAITV(8); } \
        else if (t == (NKT) - 2) { WAITV(4); } \
        BAR(); WAITL0(); \
        MMA(1); \
        BAR(); \
    }

// Kernel 1: h = silu(x@Wu^T) * (x@Wg^T).  Block: 256 rows x 128 h-cols
// (256 virtual B rows: inside each wave's 64-row block, rows 0-31 = up,
// 32-63 = gate of the same 32 h-cols -> pairing stays within-wave).
// grid = (1024/128 = 8, 16384/256 = 64), 512 threads.
__global__ __launch_bounds__(512) void moe_up_gate_p8(
    const unsigned short* __restrict__ xb, const unsigned short* __restrict__ wb,
    const int* __restrict__ bspe, unsigned short* __restrict__ hws) {
    __shared__ alignas(16) unsigned short As[32768];
    __shared__ alignas(16) unsigned short Bs[32768];

    const int t0 = threadIdx.x;
    const int lane = t0 & 63;
    const int w = t0 >> 6;                 // 0..7
    const int wr = w >> 2, wc = w & 3;
    const int row0 = blockIdx.y * 256;
    const int h0 = blockIdx.x * 128;
    const int e = find_expert(bspe, row0);

    // staging geometry (pre-swizzled global source)
    const int srow = lane >> 2;                              // 0..15
    const int gs = ((lane & 3) ^ ((lane >> 3) & 3)) * 8;     // elems
    const unsigned short* pA0 = xb + (long)(row0 + w * 16 + srow) * 2048 + gs;
    const unsigned short* pA1 = pA0 + (long)128 * 2048;
    const unsigned short* pB0; const unsigned short* pB1;
    {
        const int r0 = w * 16 + srow;        // virtual B row, issue 0
        const int r1 = r0 + 128;             // issue 1
        const int in0 = r0 & 63, in1 = r1 & 63;
        const long g0 = (long)e * 2048 + (in0 < 32 ? 0 : 1024) + h0 + (r0 >> 6) * 32 + (in0 & 31);
        const long g1 = (long)e * 2048 + (in1 < 32 ? 0 : 1024) + h0 + (r1 >> 6) * 32 + (in1 & 31);
        pB0 = wb + g0 * 2048 + gs;
        pB1 = wb + g1 * 2048 + gs;
    }

    // LDS read geometry (swizzled)
    const int l15 = lane & 15;
    const int gA = ((lane >> 4) ^ ((l15 >> 1) & 3)) * 8;     // elems
    const int arow = wr * 128 + l15;
    const int brow = wc * 64 + l15;

    float4v acc[8][4];
    #pragma unroll
    for (int m = 0; m < 8; ++m)
        #pragma unroll
        for (int n = 0; n < 4; ++n)
            acc[m][n] = (float4v){0.f, 0.f, 0.f, 0.f};

    KLOOP(32)

    // Epilogue: within each wave, frag n (up) pairs with frag n+2 (gate).
    const int rbase = row0 + wr * 128 + (lane >> 4) * 4;
    const int cbase = h0 + wc * 32 + l15;
    #pragma unroll
    for (int m = 0; m < 8; ++m)
        #pragma unroll
        for (int n = 0; n < 2; ++n)
            #pragma unroll
            for (int q = 0; q < 4; ++q) {
                const float u = acc[m][n][q];
                const float g = acc[m][n + 2][q];
                const float s = u / (1.f + __expf(-u));
                hws[(long)(rbase + m * 16 + q) * 1024 + cbase + n * 16] = f2bf(s * g);
            }
}

// Kernel 2: out = h @ Wd_e^T.  Block: 256 rows x 256 cols.
// grid = (2048/256 = 8, 64), 512 threads.
__global__ __launch_bounds__(512) void moe_down_p8(
    const unsigned short* __restrict__ hws, const unsigned short* __restrict__ wdb,
    const int* __restrict__ bspe, float* __restrict__ out) {
    __shared__ alignas(16) unsigned short As[32768];
    __shared__ alignas(16) unsigned short Bs[32768];

    const int t0 = threadIdx.x;
    const int lane = t0 & 63;
    const int w = t0 >> 6;
    const int wr = w >> 2, wc = w & 3;
    const int row0 = blockIdx.y * 256;
    const int n0 = blockIdx.x * 256;
    const int e = find_expert(bspe, row0);

    const int srow = lane >> 2;
    const int gs = ((lane & 3) ^ ((lane >> 3) & 3)) * 8;
    const unsigned short* pA0 = hws + (long)(row0 + w * 16 + srow) * 1024 + gs;
    const unsigned short* pA1 = pA0 + (long)128 * 1024;
    const unsigned short* pB0 = wdb + (long)(n0 + w * 16 + srow) * 8192 + (long)e * 1024 + gs;
    const unsigned short* pB1 = pB0 + (long)128 * 8192;

    const int l15 = lane & 15;
    const int gA = ((lane >> 4) ^ ((l15 >> 1) & 3)) * 8;
    const int arow = wr * 128 + l15;
    const int brow = wc * 64 + l15;

    float4v acc[8][4];
    #pragma unroll
    for (int m = 0; m < 8; ++m)
        #pragma unroll
        for (int n = 0; n < 4; ++n)
            acc[m][n] = (float4v){0.f, 0.f, 0.f, 0.f};

    KLOOP(16)

    const int rbase = row0 + wr * 128 + (lane >> 4) * 4;
    const int cbase = n0 + wc * 64 + l15;
    #pragma unroll
    for (int m = 0; m < 8; ++m)
        #pragma unroll
        for (int n = 0; n < 4; ++n)
            #pragma unroll
            for (int q = 0; q < 4; ++q)
                out[(long)(rbase + m * 16 + q) * 2048 + cbase + n * 16] = acc[m][n][q];
}

// ---------------------------------------------------------------------------
// OLD PATH (fallback if workspace too small) -- verbatim prior verified code.
// ---------------------------------------------------------------------------
__device__ __forceinline__ void stage_f32_tile(const float* __restrict__ src, long ld,
                                               unsigned short* lds, int t) {
    const int rr  = t >> 3;
    const int col = (t & 7) << 2;
    #pragma unroll
    for (int r = 0; r < 4; ++r) {
        const int row = rr + r * 32;
        const float4 v = *(const float4*)(src + (long)row * ld + col);
        BF4 o; o.x = f2bf(v.x); o.y = f2bf(v.y); o.z = f2bf(v.z); o.w = f2bf(v.w);
        *(BF4*)(lds + row * LDSK + col) = o;
    }
}

__global__ __launch_bounds__(256) void moe_up_gate(
    const float* __restrict__ x, const float* __restrict__ wug,
    const int* __restrict__ bspe, unsigned short* __restrict__ hws) {
    __shared__ alignas(16) unsigned short As[BM * LDSK];
    __shared__ alignas(16) unsigned short Bs[BM * LDSK];

    const int t = threadIdx.x;
    const int lane = t & 63;
    const int w = t >> 6;
    const int wr = w >> 1, wc = w & 1;
    const int bm = blockIdx.y;
    const int h0 = blockIdx.x * 64;
    const int row0 = bm * BM;

    const int e = find_expert(bspe, row0);

    const float* abase = x + (long)row0 * 2048;
    const float* bup = wug + ((long)e * 2048 + h0) * 2048;
    const float* bgt = wug + ((long)e * 2048 + 1024 + h0) * 2048;

    float4v acc[4][4];
    #pragma unroll
    for (int m = 0; m < 4; ++m)
        #pragma unroll
        for (int n = 0; n < 4; ++n)
            acc[m][n] = (float4v){0.f, 0.f, 0.f, 0.f};

    const int k8 = (lane >> 4) << 3;
    const int am = wr * 64 + (lane & 15);
    const int l15 = lane & 15;

    for (int k0 = 0; k0 < 2048; k0 += BK) {
        __syncthreads();
        stage_f32_tile(abase + k0, 2048, As, t);
        {
            const int rr  = t >> 3;
            const int col = (t & 7) << 2;
            #pragma unroll
            for (int r = 0; r < 4; ++r) {
                const int row = rr + r * 32;
                const float* p = (row < 64 ? bup + (long)row * 2048
                                           : bgt + (long)(row - 64) * 2048) + k0 + col;
                const float4 v = *(const float4*)p;
                BF4 o; o.x = f2bf(v.x); o.y = f2bf(v.y); o.z = f2bf(v.z); o.w = f2bf(v.w);
                *(BF4*)(Bs + row * LDSK + col) = o;
            }
        }
        __syncthreads();

        short8 a[4], b[4];
        #pragma unroll
        for (int m = 0; m < 4; ++m)
            a[m] = *(const short8*)(As + (am + m * 16) * LDSK + k8);
        #pragma unroll
        for (int n = 0; n < 4; ++n) {
            const int rb = (n < 2) ? (wc * 32 + n * 16) : (64 + wc * 32 + (n - 2) * 16);
            b[n] = *(const short8*)(Bs + (rb + l15) * LDSK + k8);
        }
        #pragma unroll
        for (int m = 0; m < 4; ++m)
            #pragma unroll
            for (int n = 0; n < 4; ++n)
                acc[m][n] = __builtin_amdgcn_mfma_f32_16x16x32_bf16(a[m], b[n], acc[m][n], 0, 0, 0);
    }

    const int rbase = row0 + wr * 64 + (lane >> 4) * 4;
    const int cbase = h0 + wc * 32 + l15;
    #pragma unroll
    for (int m = 0; m < 4; ++m)
        #pragma unroll
        for (int n = 0; n < 2; ++n)
            #pragma unroll
            for (int q = 0; q < 4; ++q) {
                const float u = acc[m][n][q];
                const float g = acc[m][n + 2][q];
                const float s = u / (1.f + __expf(-u));
                hws[(long)(rbase + m * 16 + q) * 1024 + cbase + n * 16] = f2bf(s * g);
            }
}

__global__ __launch_bounds__(256) void moe_down(
    const unsigned short* __restrict__ hws, const float* __restrict__ wd,
    const int* __restrict__ bspe, float* __restrict__ out) {
    __shared__ alignas(16) unsigned short As[BM * LDSK];
    __shared__ alignas(16) unsigned short Bs[BM * LDSK];

    const int t = threadIdx.x;
    const int lane = t & 63;
    const int w = t >> 6;
    const int wr = w >> 1, wc = w & 1;
    const int bm = blockIdx.y;
    const int n0 = blockIdx.x * BM;
    const int row0 = bm * BM;

    const int e = find_expert(bspe, row0);

    const unsigned short* abase = hws + (long)row0 * 1024;
    const float* bbase = wd + (long)n0 * 8192 + e * 1024;

    float4v acc[4][4];
    #pragma unroll
    for (int m = 0; m < 4; ++m)
        #pragma unroll
        for (int n = 0; n < 4; ++n)
            acc[m][n] = (float4v){0.f, 0.f, 0.f, 0.f};

    const int k8 = (lane >> 4) << 3;
    const int am = wr * 64 + (lane & 15);
    const int l15 = lane & 15;

    for (int k0 = 0; k0 < 1024; k0 += BK) {
        __syncthreads();
        {
            const int row = t >> 2;
            const int col = (t & 3) << 3;
            #pragma unroll
            for (int r = 0; r < 2; ++r) {
                const I4 v = *(const I4*)(abase + (long)(row + r * 64) * 1024 + k0 + col);
                *(I4*)(As + (row + r * 64) * LDSK + col) = v;
            }
        }
        stage_f32_tile(bbase + k0, 8192, Bs, t);
        __syncthreads();

        short8 a[4], b[4];
        #pragma unroll
        for (int m = 0; m < 4; ++m)
            a[m] = *(const short8*)(As + (am + m * 16) * LDSK + k8);
        #pragma unroll
        for (int n = 0; n < 4; ++n)
            b[n] = *(const short8*)(Bs + (wc * 64 + n * 16 + l15) * LDSK + k8);
        #pragma unroll
        for (int m = 0; m < 4; ++m)
            #pragma unroll
            for (int n = 0; n < 4; ++n)
                acc[m][n] = __builtin_amdgcn_mfma_f32_16x16x32_bf16(a[m], b[n], acc[m][n], 0, 0, 0);
    }

    const int rbase = row0 + wr * 64 + (lane >> 4) * 4;
    const int cbase = n0 + wc * 64 + l15;
    #pragma unroll
    for (int m = 0; m < 4; ++m)
        #pragma unroll
        for (int n = 0; n < 4; ++n)
            #pragma unroll
            for (int q = 0; q < 4; ++q)
                out[(long)(rbase + m * 16 + q) * 2048 + cbase + n * 16] = acc[m][n][q];
}

// ---------------------------------------------------------------------------
extern "C" void kernel_launch(void* const* d_in, const int* in_sizes, int n_in,
                              void* d_out, int out_size, void* d_ws, size_t ws_size,
                              hipStream_t stream) {
    const float* x   = (const float*)d_in[0];
    const float* wug = (const float*)d_in[1];
    const float* wd  = (const float*)d_in[2];
    const int*  bspe = (const int*)d_in[3];
    float* out = (float*)d_out;

    const size_t SZ_XB  = 16384UL * 2048UL * 2UL;   // 67.1 MB bf16 x
    const size_t SZ_WB  = 16384UL * 2048UL * 2UL;   // 67.1 MB bf16 w_up_gate
    const size_t SZ_H   = 16384UL * 1024UL * 2UL;   // 33.6 MB bf16 h
    const size_t NEED   = SZ_XB + SZ_WB + SZ_H;

    if (ws_size >= NEED) {
        unsigned short* xb  = (unsigned short*)d_ws;
        unsigned short* wb  = (unsigned short*)((char*)d_ws + SZ_XB);
        unsigned short* hws = (unsigned short*)((char*)d_ws + SZ_XB + SZ_WB);
        unsigned short* wdb = (unsigned short*)d_ws;   // overlay: x_bf dead after up_gate

        f32_to_bf16<<<2048, 256, 0, stream>>>(x,   xb,  16384L * 2048L);
        f32_to_bf16<<<2048, 256, 0, stream>>>(wug, wb,  16384L * 2048L);
        moe_up_gate_p8<<<dim3(8, 64), dim3(512), 0, stream>>>(xb, wb, bspe, hws);
        f32_to_bf16<<<1024, 256, 0, stream>>>(wd,  wdb, 2048L * 8192L);
        moe_down_p8<<<dim3(8, 64), dim3(512), 0, stream>>>(hws, wdb, bspe, out);
    } else {
        unsigned short* hws = (unsigned short*)d_ws;
        moe_up_gate<<<dim3(16, 128), dim3(256), 0, stream>>>(x, wug, bspe, hws);
        moe_down  <<<dim3(16, 128), dim3(256), 0, stream>>>(hws, wd, bspe, out);
    }
}